// Round 1
// baseline (522.900 us; speedup 1.0000x reference)
//
#include <hip/hip_runtime.h>

namespace {

constexpr int kB  = 16;
constexpr int kNC = 31;
constexpr int kNX = 256;   // rows (H)
constexpr int kNY = 256;   // cols (W), fastest-varying
constexpr int kNO = 3;
constexpr int kKS = 17;

constexpr int TX = 64;          // output cols per block
constexpr int TY = 32;          // output rows per block
constexpr int HTX = TX + 16;    // 80 staged cols (halo +-8)
constexpr int HTY = TY + 8;     // 40 staged rows (halo +-4)
constexpr int XPITCH = 81;      // odd pitch -> <=2-way bank aliasing (free)
constexpr int WPITCH = 12;      // 9 taps padded to 12 for aligned b128 reads
constexpr int NOC = kNO * kNC;  // 93

// out[b,o,y,x] = sum_{c,dy',dx'} x[b,c, y+dy'-4, x + (cx-8) + dx'-4] * w[oc][dy'][dx']
// with w[oc][dy'][dx'] = relu(vk[oc*81 + dy'*9 + dx']), cx from locations[oc*81].
__global__ __launch_bounds__(256, 2)
void disperse_conv(const float* __restrict__ x,
                   const float* __restrict__ vk,
                   const int* __restrict__ loc,
                   float* __restrict__ out)
{
    __shared__ __align__(16) float wlds[NOC * 9 * WPITCH];  // 40176 B
    __shared__ __align__(16) float xtile[HTY * XPITCH];     // 12960 B
    __shared__ int sol[NOC];                                // so = sx+4 in [0,8]

    const int tid = threadIdx.x;
    const int x0 = blockIdx.x * TX;
    const int y0 = blockIdx.y * TY;
    const int b  = blockIdx.z;

    // --- stage ReLU'd weights once (padded rows of 12) ---
    for (int i = tid; i < NOC * 9 * WPITCH; i += 256) {
        int dx = i % WPITCH;
        int rowi = i / WPITCH;          // oc*9 + dy
        float v = 0.0f;
        if (dx < 9) {
            float t = vk[rowi * 9 + dx];
            v = t > 0.0f ? t : 0.0f;
        }
        wlds[i] = v;
    }
    if (tid < NOC) {
        // locations[oc*81] = ((oc*17 + 4)*17) + cx - 4  ->  recover cx
        int l0 = loc[tid * 81];
        int cx = l0 - (tid * kKS + 4) * kKS + 4;
        sol[tid] = cx - 4;              // so = (cx-8) + 4
    }

    const int tx = tid & 7;             // 8 threads across x
    const int ty = tid >> 3;            // 32 threads down y
    const int xo = tx * 8;              // 8 consecutive output cols per thread

    float acc[kNO][8];
    #pragma unroll
    for (int o = 0; o < kNO; ++o)
        #pragma unroll
        for (int j = 0; j < 8; ++j)
            acc[o][j] = 0.0f;

    for (int c = 0; c < kNC; ++c) {
        __syncthreads();   // protect previous tile reads (and weight staging at c=0)
        // --- stage x tile: rows y0-4..y0+35, cols x0-8..x0+71 (zero-padded) ---
        const float* xc = x + (size_t)(b * kNC + c) * kNX * kNY;
        for (int i = tid; i < HTY * (HTX / 4); i += 256) {   // 800 float4
            int r  = i / (HTX / 4);
            int cv = (i - r * (HTX / 4)) * 4;
            int gy = y0 - 4 + r;
            int gx = x0 - 8 + cv;        // multiple of 4 -> aligned, never straddles
            float4 v = make_float4(0.f, 0.f, 0.f, 0.f);
            if ((unsigned)gy < (unsigned)kNX && (unsigned)gx < (unsigned)kNY)
                v = *(const float4*)(xc + (size_t)gy * kNY + gx);
            float* d = &xtile[r * XPITCH + cv];
            d[0] = v.x; d[1] = v.y; d[2] = v.z; d[3] = v.w;
        }
        __syncthreads();

        #pragma unroll
        for (int o = 0; o < kNO; ++o) {
            const int oc = o * kNC + c;
            const int so = sol[oc];                      // per-(o,c) shift, runtime
            const float* wbase = &wlds[oc * 9 * WPITCH];
            #pragma unroll 1
            for (int dy = 0; dy < 9; ++dy) {
                // 16 x-values cover 8 outputs x 9 taps at this order's shift
                const float* xt = &xtile[(ty + dy) * XPITCH + xo + so];
                float xr[16];
                #pragma unroll
                for (int i = 0; i < 16; ++i) xr[i] = xt[i];
                const float4* wv = (const float4*)(wbase + dy * WPITCH);
                float4 w0 = wv[0], w1 = wv[1], w2 = wv[2];
                float w[9] = {w0.x, w0.y, w0.z, w0.w, w1.x, w1.y, w1.z, w1.w, w2.x};
                #pragma unroll
                for (int dx = 0; dx < 9; ++dx)
                    #pragma unroll
                    for (int j = 0; j < 8; ++j)
                        acc[o][j] = fmaf(w[dx], xr[j + dx], acc[o][j]);
            }
        }
    }

    // --- epilogue: 3 orders x 8 cols per thread, float4 stores ---
    #pragma unroll
    for (int o = 0; o < kNO; ++o) {
        size_t base = (((size_t)b * kNO + o) * kNX + (size_t)(y0 + ty)) * kNY
                      + (size_t)(x0 + xo);
        *(float4*)(out + base)     = make_float4(acc[o][0], acc[o][1], acc[o][2], acc[o][3]);
        *(float4*)(out + base + 4) = make_float4(acc[o][4], acc[o][5], acc[o][6], acc[o][7]);
    }
}

} // namespace

extern "C" void kernel_launch(void* const* d_in, const int* in_sizes, int n_in,
                              void* d_out, int out_size, void* d_ws, size_t ws_size,
                              hipStream_t stream)
{
    const float* x  = (const float*)d_in[0];
    const float* vk = (const float*)d_in[1];
    const int* loc  = (const int*)d_in[2];
    float* out = (float*)d_out;

    dim3 grid(kNY / TX, kNX / TY, kB);   // (4, 8, 16) = 512 blocks
    dim3 block(256);
    hipLaunchKernelGGL(disperse_conv, grid, block, 0, stream, x, vk, loc, out);
}